// Round 1
// baseline (3877.348 us; speedup 1.0000x reference)
//
#include <hip/hip_runtime.h>

// ============================================================================
// seq2seq + attention on MI355X.
// Shapes: B=32, Te=64, Td=32 (31 dec steps), E=256, H=512, V=32000, G=4H=2048.
// Strategy:
//   - gather embeddings -> bf16
//   - XF/XB/XD = emb @ Wih^T + b  (bf16 MFMA GEMM, fp32 out)
//   - encoder fwd+bwd LSTM: 64 per-step fp32 kernels (both dirs per launch)
//   - enc_feat = enc_output @ W_ef^T + b_ef (MFMA)
//   - decoder: 31 steps x {gates, df, attention} fp32 kernels;
//     [h_t, ctx_t] collected into bf16 ACAT
//   - logits = ACAT @ W_out^T + b_out : one big bf16 MFMA GEMM (97.5 GFLOP)
// Workspace needed: ~58 MB.
// ============================================================================

typedef __attribute__((ext_vector_type(8))) short bfrag_t;
typedef __attribute__((ext_vector_type(4))) float f4_t;

static __device__ __forceinline__ float bf2f(unsigned short u) {
  union { float f; unsigned int i; } v; v.i = ((unsigned int)u) << 16; return v.f;
}
static __device__ __forceinline__ unsigned short f2bf(float f) {
  union { float f; unsigned int i; } v; v.f = f;
  unsigned int r = v.i + 0x7FFFu + ((v.i >> 16) & 1u);  // RNE
  return (unsigned short)(r >> 16);
}
static __device__ __forceinline__ float sigm(float x) { return 1.f / (1.f + expf(-x)); }

#define GLDS16(g, l)                                                        \
  __builtin_amdgcn_global_load_lds(                                         \
      (const __attribute__((address_space(1))) void*)(g),                   \
      (__attribute__((address_space(3))) void*)(l), 16, 0, 0)

// ---------------------------------------------------------------------------
// Generic C = A(bf16, MxK, lda) @ B(fp32, NxldB row-major, col offset)^T + bias
// C fp32 (ldc), rows < Mvalid stored. Tile 128x128, BK=32, 4 waves.
// mfma_f32_16x16x32_bf16: A/B frag: row=lane&15, k=(lane>>4)*8+e (contig 8);
// C/D: col=lane&15, row=(lane>>4)*4+reg.
// ---------------------------------------------------------------------------
__global__ __launch_bounds__(256) void gemm_bt_kernel(
    const unsigned short* __restrict__ A, int lda,
    const float* __restrict__ B, int ldb, int bcol0,
    const float* __restrict__ bias,
    float* __restrict__ C, int ldc, int Mvalid, int K) {
  __shared__ unsigned short As[128 * 32];
  __shared__ unsigned short Bs[128 * 32];
  const int tid = threadIdx.x;
  const int w = tid >> 6, lane = tid & 63;
  const int wr = (w >> 1) * 64, wc = (w & 1) * 64;
  const int l15 = lane & 15, l4 = lane >> 4;
  const int m0 = blockIdx.x * 128, n0 = blockIdx.y * 128;

  // A staging via global_load_lds: lane's 16B goes to ldsbase + lane*16.
  const int arow = w * 16 + (lane >> 2);
  const int acol = (lane & 3) * 8;
  const unsigned short* Ag = A + (size_t)(m0 + arow) * lda + acol;

  // B staging: reg-load fp32, convert to bf16, ds_write.
  const int brow = tid >> 1;
  const int bcol = (tid & 1) * 16;
  const float* Bg = B + (size_t)(n0 + brow) * ldb + bcol0 + bcol;
  unsigned short* Bsw = Bs + brow * 32 + bcol;

  f4_t acc[4][4];
#pragma unroll
  for (int i = 0; i < 4; ++i)
#pragma unroll
    for (int j = 0; j < 4; ++j) {
      acc[i][j].x = 0.f; acc[i][j].y = 0.f; acc[i][j].z = 0.f; acc[i][j].w = 0.f;
    }

  for (int kt = 0; kt < K; kt += 32) {
    GLDS16(Ag + kt, As + w * 512);
    GLDS16(Ag + (size_t)64 * lda + kt, As + (4 + w) * 512);
    float4 q0 = *(const float4*)(Bg + kt);
    float4 q1 = *(const float4*)(Bg + kt + 4);
    float4 q2 = *(const float4*)(Bg + kt + 8);
    float4 q3 = *(const float4*)(Bg + kt + 12);
    union { unsigned int u[8]; uint4 q[2]; } pk;
    pk.u[0] = (unsigned int)f2bf(q0.x) | ((unsigned int)f2bf(q0.y) << 16);
    pk.u[1] = (unsigned int)f2bf(q0.z) | ((unsigned int)f2bf(q0.w) << 16);
    pk.u[2] = (unsigned int)f2bf(q1.x) | ((unsigned int)f2bf(q1.y) << 16);
    pk.u[3] = (unsigned int)f2bf(q1.z) | ((unsigned int)f2bf(q1.w) << 16);
    pk.u[4] = (unsigned int)f2bf(q2.x) | ((unsigned int)f2bf(q2.y) << 16);
    pk.u[5] = (unsigned int)f2bf(q2.z) | ((unsigned int)f2bf(q2.w) << 16);
    pk.u[6] = (unsigned int)f2bf(q3.x) | ((unsigned int)f2bf(q3.y) << 16);
    pk.u[7] = (unsigned int)f2bf(q3.z) | ((unsigned int)f2bf(q3.w) << 16);
    *(uint4*)(Bsw) = pk.q[0];
    *(uint4*)(Bsw + 8) = pk.q[1];
    __syncthreads();  // drains vmcnt (global_load_lds) + lgkm (ds_write)
    bfrag_t af[4], bfv[4];
#pragma unroll
    for (int m = 0; m < 4; ++m)
      af[m] = *(const bfrag_t*)(As + (wr + m * 16 + l15) * 32 + l4 * 8);
#pragma unroll
    for (int n = 0; n < 4; ++n)
      bfv[n] = *(const bfrag_t*)(Bs + (wc + n * 16 + l15) * 32 + l4 * 8);
#pragma unroll
    for (int m = 0; m < 4; ++m)
#pragma unroll
      for (int n = 0; n < 4; ++n)
        acc[m][n] = __builtin_amdgcn_mfma_f32_16x16x32_bf16(af[m], bfv[n], acc[m][n], 0, 0, 0);
    __syncthreads();
  }

  const int crb = l4 * 4;
#pragma unroll
  for (int m = 0; m < 4; ++m)
#pragma unroll
    for (int n = 0; n < 4; ++n)
#pragma unroll
      for (int r = 0; r < 4; ++r) {
        int gr = m0 + wr + m * 16 + crb + r;
        if (gr < Mvalid) {
          int gc = n0 + wc + n * 16 + l15;
          C[(size_t)gr * ldc + gc] = acc[m][n][r] + bias[gc];
        }
      }
}

// ---------------------------------------------------------------------------
// Embedding gathers -> bf16 rows
// ---------------------------------------------------------------------------
__global__ void gather_enc_kernel(const int* __restrict__ texts,
                                  const float* __restrict__ table,
                                  unsigned short* __restrict__ out) {
  const int row = blockIdx.x;  // b*64+t, 2048 rows
  const int tok = texts[row];
  const float4 v = *(const float4*)(table + (size_t)tok * 256 + threadIdx.x * 4);
  unsigned short* o = out + (size_t)row * 256 + threadIdx.x * 4;
  o[0] = f2bf(v.x); o[1] = f2bf(v.y); o[2] = f2bf(v.z); o[3] = f2bf(v.w);
}

__global__ void gather_dec_kernel(const int* __restrict__ texts,
                                  const float* __restrict__ table,
                                  unsigned short* __restrict__ out) {
  const int row = blockIdx.x;  // b*31+t, 1024 rows (pad 992..1023 = 0)
  unsigned short* o = out + (size_t)row * 256 + threadIdx.x * 4;
  if (row >= 992) { o[0] = 0; o[1] = 0; o[2] = 0; o[3] = 0; return; }
  const int b = row / 31, t2 = row - b * 31;
  const int tok = texts[b * 32 + t2];
  const float4 v = *(const float4*)(table + (size_t)tok * 256 + threadIdx.x * 4);
  o[0] = f2bf(v.x); o[1] = f2bf(v.y); o[2] = f2bf(v.z); o[3] = f2bf(v.w);
}

// ---------------------------------------------------------------------------
// Encoder LSTM step (both directions). 256 blocks: dir=bi>>7, 4 units each.
// HENC layout: [dir][h/c][pp][32*512] fp32.
// ---------------------------------------------------------------------------
__global__ __launch_bounds__(256) void enc_step_kernel(
    const float* __restrict__ XF, const float* __restrict__ XB,
    const float* __restrict__ Whh_f, const float* __restrict__ Whh_b,
    const float* __restrict__ mask, float* __restrict__ HENC,
    unsigned short* __restrict__ ENCO, float* __restrict__ HFIN, int s) {
  const int bi = blockIdx.x;
  const int dir = bi >> 7;
  const int u0 = (bi & 127) * 4;
  const int t = dir ? (63 - s) : s;
  const int pp = s & 1;
  const int tid = threadIdx.x;
  const int j = tid >> 4, bp = tid & 15;
  const int gate = j >> 2, ul = j & 3;
  const int grow = gate * 512 + u0 + ul;
  const int b0 = bp * 2, b1 = b0 + 1;

  const float* X = dir ? XB : XF;
  const float* W = dir ? Whh_b : Whh_f;
  float* Hh = HENC + (size_t)(dir * 2 + 0) * 2 * 16384;
  float* Hc = HENC + (size_t)(dir * 2 + 1) * 2 * 16384;

  __shared__ float Hl[32][132];
  __shared__ float Wl[16][132];
  __shared__ float Gl[16][32];

  float a0 = 0.f, a1 = 0.f;
  for (int kc = 0; kc < 512; kc += 128) {
#pragma unroll
    for (int i = 0; i < 4; ++i) {
      int idx = tid + i * 256;
      int r = idx >> 5, c = (idx & 31) * 4;
      *(float4*)&Hl[r][c] = *(const float4*)(Hh + pp * 16384 + r * 512 + kc + c);
    }
#pragma unroll
    for (int i = 0; i < 2; ++i) {
      int idx = tid + i * 256;
      int r = idx >> 5, c = (idx & 31) * 4;
      int wrow = (r >> 2) * 512 + u0 + (r & 3);
      *(float4*)&Wl[r][c] = *(const float4*)(W + (size_t)wrow * 512 + kc + c);
    }
    __syncthreads();
#pragma unroll
    for (int k = 0; k < 128; k += 4) {
      float4 wv = *(const float4*)&Wl[j][k];
      float4 h0 = *(const float4*)&Hl[b0][k];
      float4 h1 = *(const float4*)&Hl[b1][k];
      a0 += wv.x * h0.x + wv.y * h0.y + wv.z * h0.z + wv.w * h0.w;
      a1 += wv.x * h1.x + wv.y * h1.y + wv.z * h1.z + wv.w * h1.w;
    }
    __syncthreads();
  }
  a0 += X[((size_t)b0 * 64 + t) * 2048 + grow];
  a1 += X[((size_t)b1 * 64 + t) * 2048 + grow];
  Gl[j][b0] = a0;
  Gl[j][b1] = a1;
  __syncthreads();
  if (tid < 128) {
    const int b = tid & 31, uo = tid >> 5;
    const int u = u0 + uo;
    float gi = Gl[uo][b], gf = Gl[4 + uo][b], gg = Gl[8 + uo][b], go = Gl[12 + uo][b];
    float c_old = Hc[pp * 16384 + b * 512 + u];
    float h_old = Hh[pp * 16384 + b * 512 + u];
    float cn = sigm(gf) * c_old + sigm(gi) * tanhf(gg);
    float hn = sigm(go) * tanhf(cn);
    float m = mask[b * 64 + t];
    float hmix = m * hn + (1.f - m) * h_old;
    float cmix = m * cn + (1.f - m) * c_old;
    Hh[(pp ^ 1) * 16384 + b * 512 + u] = hmix;
    Hc[(pp ^ 1) * 16384 + b * 512 + u] = cmix;
    ENCO[((size_t)b * 64 + t) * 1024 + dir * 512 + u] = f2bf(hmix * m);
    if (s == 63) {
      HFIN[dir * 16384 + b * 512 + u] = hmix;        // hf / hb
      HFIN[(2 + dir) * 16384 + b * 512 + u] = cmix;  // cf / cb
    }
  }
}

// ---------------------------------------------------------------------------
// dec_h = relu([hf,hb]@W_h^T + b_h), dec_c = relu([cf,cb]@W_c^T + b_c)
// 128 blocks: mat=bi>>6, 8 outputs x 32 b per block. Writes HDEC pp=0.
// HDEC layout: [h/c][pp][32*512].
// ---------------------------------------------------------------------------
__global__ __launch_bounds__(256) void dec_init_kernel(
    const float* __restrict__ HFIN, const float* __restrict__ W_h,
    const float* __restrict__ b_h, const float* __restrict__ W_c,
    const float* __restrict__ b_c, float* __restrict__ HDEC) {
  const int bi = blockIdx.x;
  const int mat = bi >> 6;
  const int j0 = (bi & 63) * 8;
  const int tid = threadIdx.x;
  const int j = tid >> 5, b = tid & 31;
  const float* W = mat ? W_c : W_h;
  const float* bias = mat ? b_c : b_h;
  const float* x0 = HFIN + (mat ? 2 : 0) * 16384;
  const float* x1 = HFIN + (mat ? 3 : 1) * 16384;

  __shared__ float Xl[32][132];
  __shared__ float Wl[8][132];
  float acc = 0.f;
  for (int kc = 0; kc < 1024; kc += 128) {
#pragma unroll
    for (int i = 0; i < 4; ++i) {
      int idx = tid + i * 256;
      int r = idx >> 5, c = (idx & 31) * 4;
      const float* src = (kc < 512) ? (x0 + r * 512 + kc + c) : (x1 + r * 512 + (kc - 512) + c);
      *(float4*)&Xl[r][c] = *(const float4*)src;
    }
    {
      int r = tid >> 5, c = (tid & 31) * 4;
      *(float4*)&Wl[r][c] = *(const float4*)(W + (size_t)(j0 + r) * 1024 + kc + c);
    }
    __syncthreads();
#pragma unroll
    for (int k = 0; k < 128; k += 4) {
      float4 wv = *(const float4*)&Wl[j][k];
      float4 xv = *(const float4*)&Xl[b][k];
      acc += wv.x * xv.x + wv.y * xv.y + wv.z * xv.z + wv.w * xv.w;
    }
    __syncthreads();
  }
  float v = acc + bias[j0 + j];
  HDEC[mat * 2 * 16384 + b * 512 + j0 + j] = fmaxf(v, 0.f);
}

// ---------------------------------------------------------------------------
// Decoder gates: g = XD[b,t] + ctx@Wih_d[:,256:]^T + h@Whh_d^T -> h,c update.
// 128 blocks (4 units each). CTX layout [pp][32*1024].
// ---------------------------------------------------------------------------
__global__ __launch_bounds__(256) void dec_gates_kernel(
    const float* __restrict__ XD, const float* __restrict__ Wih_d,
    const float* __restrict__ Whh_d, float* __restrict__ HDEC,
    const float* __restrict__ CTX, unsigned short* __restrict__ ACAT, int t) {
  const int u0 = blockIdx.x * 4;
  const int dp = t & 1;
  const int tid = threadIdx.x;
  const int j = tid >> 4, bp = tid & 15;
  const int gate = j >> 2, ul = j & 3;
  const int grow = gate * 512 + u0 + ul;
  const int b0 = bp * 2, b1 = b0 + 1;
  const float* hsrc = HDEC + dp * 16384;
  const float* csrc = HDEC + 2 * 16384 + dp * 16384;
  const float* ctxsrc = CTX + dp * 32768;

  __shared__ float Xl[32][132];
  __shared__ float Wl[16][132];
  __shared__ float Gl[16][32];

  float a0 = 0.f, a1 = 0.f;
  for (int kc = 0; kc < 1536; kc += 128) {
#pragma unroll
    for (int i = 0; i < 4; ++i) {
      int idx = tid + i * 256;
      int r = idx >> 5, c = (idx & 31) * 4;
      const float* src = (kc < 1024) ? (ctxsrc + r * 1024 + kc + c)
                                     : (hsrc + r * 512 + (kc - 1024) + c);
      *(float4*)&Xl[r][c] = *(const float4*)src;
    }
#pragma unroll
    for (int i = 0; i < 2; ++i) {
      int idx = tid + i * 256;
      int r = idx >> 5, c = (idx & 31) * 4;
      int wrow = (r >> 2) * 512 + u0 + (r & 3);
      const float* wsrc = (kc < 1024) ? (Wih_d + (size_t)wrow * 1280 + 256 + kc + c)
                                      : (Whh_d + (size_t)wrow * 512 + (kc - 1024) + c);
      *(float4*)&Wl[r][c] = *(const float4*)wsrc;
    }
    __syncthreads();
#pragma unroll
    for (int k = 0; k < 128; k += 4) {
      float4 wv = *(const float4*)&Wl[j][k];
      float4 x0 = *(const float4*)&Xl[b0][k];
      float4 x1 = *(const float4*)&Xl[b1][k];
      a0 += wv.x * x0.x + wv.y * x0.y + wv.z * x0.z + wv.w * x0.w;
      a1 += wv.x * x1.x + wv.y * x1.y + wv.z * x1.z + wv.w * x1.w;
    }
    __syncthreads();
  }
  a0 += XD[((size_t)b0 * 31 + t) * 2048 + grow];
  a1 += XD[((size_t)b1 * 31 + t) * 2048 + grow];
  Gl[j][b0] = a0;
  Gl[j][b1] = a1;
  __syncthreads();
  if (tid < 128) {
    const int b = tid & 31, uo = tid >> 5;
    const int u = u0 + uo;
    float gi = Gl[uo][b], gf = Gl[4 + uo][b], gg = Gl[8 + uo][b], go = Gl[12 + uo][b];
    float c_old = csrc[b * 512 + u];
    float cn = sigm(gf) * c_old + sigm(gi) * tanhf(gg);
    float hn = sigm(go) * tanhf(cn);
    HDEC[(dp ^ 1) * 16384 + b * 512 + u] = hn;
    HDEC[2 * 16384 + (dp ^ 1) * 16384 + b * 512 + u] = cn;
    ACAT[((size_t)b * 31 + t) * 1536 + u] = f2bf(hn);
  }
}

// ---------------------------------------------------------------------------
// df = [h,c] @ W_df^T + b_df. 64 blocks (16 outputs x 32 b).
// ---------------------------------------------------------------------------
__global__ __launch_bounds__(256) void dec_df_kernel(
    const float* __restrict__ HDEC, const float* __restrict__ W_df,
    const float* __restrict__ b_df, float* __restrict__ DF, int t) {
  const int j0 = blockIdx.x * 16;
  const int dp1 = (t & 1) ^ 1;
  const int tid = threadIdx.x;
  const int j = tid >> 4, bp = tid & 15;
  const int b0 = bp * 2, b1 = b0 + 1;
  const float* hsrc = HDEC + dp1 * 16384;
  const float* csrc = HDEC + 2 * 16384 + dp1 * 16384;
  __shared__ float Xl[32][132];
  __shared__ float Wl[16][132];
  float a0 = 0.f, a1 = 0.f;
  for (int kc = 0; kc < 1024; kc += 128) {
#pragma unroll
    for (int i = 0; i < 4; ++i) {
      int idx = tid + i * 256;
      int r = idx >> 5, c = (idx & 31) * 4;
      const float* src = (kc < 512) ? (hsrc + r * 512 + kc + c) : (csrc + r * 512 + (kc - 512) + c);
      *(float4*)&Xl[r][c] = *(const float4*)src;
    }
#pragma unroll
    for (int i = 0; i < 2; ++i) {
      int idx = tid + i * 256;
      int r = idx >> 5, c = (idx & 31) * 4;
      *(float4*)&Wl[r][c] = *(const float4*)(W_df + (size_t)(j0 + r) * 1024 + kc + c);
    }
    __syncthreads();
#pragma unroll
    for (int k = 0; k < 128; k += 4) {
      float4 wv = *(const float4*)&Wl[j][k];
      float4 x0 = *(const float4*)&Xl[b0][k];
      float4 x1 = *(const float4*)&Xl[b1][k];
      a0 += wv.x * x0.x + wv.y * x0.y + wv.z * x0.z + wv.w * x0.w;
      a1 += wv.x * x1.x + wv.y * x1.y + wv.z * x1.z + wv.w * x1.w;
    }
    __syncthreads();
  }
  const int jg = j0 + j;
  DF[b0 * 1024 + jg] = a0 + b_df[jg];
  DF[b1 * 1024 + jg] = a1 + b_df[jg];
}

// ---------------------------------------------------------------------------
// scores = df . enc_feat -> masked softmax -> ctx = a @ enc_output.
// 32 blocks (one per batch).
// ---------------------------------------------------------------------------
__global__ __launch_bounds__(256) void dec_attn_kernel(
    const float* __restrict__ DF, const float* __restrict__ EF,
    const unsigned short* __restrict__ ENCO, const float* __restrict__ mask,
    float* __restrict__ CTX, unsigned short* __restrict__ ACAT, int t) {
  const int b = blockIdx.x;
  const int tid = threadIdx.x;
  const int dpw = (t & 1) ^ 1;
  __shared__ float dfl[1024];
  __shared__ float scl[64];
  __shared__ float al[64];
  for (int i = tid; i < 1024; i += 256) dfl[i] = DF[b * 1024 + i];
  __syncthreads();
  {
    const int s = tid >> 2, part = tid & 3;
    const float* ef = EF + ((size_t)b * 64 + s) * 1024 + part * 256;
    float acc = 0.f;
    for (int k = 0; k < 256; k += 4) {
      float4 e = *(const float4*)(ef + k);
      float4 d = *(const float4*)(&dfl[part * 256 + k]);
      acc += e.x * d.x + e.y * d.y + e.z * d.z + e.w * d.w;
    }
    acc += __shfl_xor(acc, 1);
    acc += __shfl_xor(acc, 2);
    if (part == 0) scl[s] = acc;
  }
  __syncthreads();
  if (tid < 64) {
    float v = scl[tid];
    float mx = v;
#pragma unroll
    for (int o = 32; o >= 1; o >>= 1) mx = fmaxf(mx, __shfl_xor(mx, o));
    float e = expf(v - mx) * mask[b * 64 + tid];
    float sm = e;
#pragma unroll
    for (int o = 32; o >= 1; o >>= 1) sm += __shfl_xor(sm, o);
    al[tid] = e / sm;
  }
  __syncthreads();
  float c0 = 0.f, c1 = 0.f, c2 = 0.f, c3 = 0.f;
  for (int tp = 0; tp < 64; ++tp) {
    float a = al[tp];
    const unsigned short* eo = ENCO + ((size_t)b * 64 + tp) * 1024 + tid;
    c0 += a * bf2f(eo[0]);
    c1 += a * bf2f(eo[256]);
    c2 += a * bf2f(eo[512]);
    c3 += a * bf2f(eo[768]);
  }
  float* cp = CTX + dpw * 32768 + b * 1024;
  unsigned short* ap = ACAT + ((size_t)b * 31 + t) * 1536 + 512;
  cp[tid] = c0; cp[tid + 256] = c1; cp[tid + 512] = c2; cp[tid + 768] = c3;
  ap[tid] = f2bf(c0); ap[tid + 256] = f2bf(c1);
  ap[tid + 512] = f2bf(c2); ap[tid + 768] = f2bf(c3);
}

// ============================================================================
extern "C" void kernel_launch(void* const* d_in, const int* in_sizes, int n_in,
                              void* d_out, int out_size, void* d_ws, size_t ws_size,
                              hipStream_t stream) {
  const int*   enc_texts = (const int*)  d_in[0];
  const float* enc_mask  = (const float*)d_in[1];
  const int*   dec_texts = (const int*)  d_in[2];
  const float* enc_emb   = (const float*)d_in[3];
  const float* dec_emb   = (const float*)d_in[4];
  const float* Wih_f = (const float*)d_in[5];
  const float* Whh_f = (const float*)d_in[6];
  const float* b_f   = (const float*)d_in[7];
  const float* Wih_b = (const float*)d_in[8];
  const float* Whh_b = (const float*)d_in[9];
  const float* b_b   = (const float*)d_in[10];
  const float* Wih_d = (const float*)d_in[11];
  const float* Whh_d = (const float*)d_in[12];
  const float* b_d   = (const float*)d_in[13];
  const float* W_h   = (const float*)d_in[14];
  const float* b_h   = (const float*)d_in[15];
  const float* W_c   = (const float*)d_in[16];
  const float* b_c   = (const float*)d_in[17];
  const float* W_df  = (const float*)d_in[18];
  const float* b_df  = (const float*)d_in[19];
  const float* W_ef  = (const float*)d_in[20];
  const float* b_ef  = (const float*)d_in[21];
  const float* W_out = (const float*)d_in[22];
  const float* b_out = (const float*)d_in[23];
  float* out = (float*)d_out;

  char* ws = (char*)d_ws;
  size_t off = 0;
  auto alloc = [&](size_t bytes) {
    char* p = ws + off;
    off += (bytes + 255) & ~(size_t)255;
    return p;
  };
  // --- zero-init group (single memset) ---
  float* HENC = (float*)alloc((size_t)8 * 16384 * 4);   // [dir][h/c][pp]
  float* HDEC = (float*)alloc((size_t)4 * 16384 * 4);   // [h/c][pp]
  float* CTX  = (float*)alloc((size_t)2 * 32768 * 4);   // [pp]
  unsigned short* ACAT = (unsigned short*)alloc((size_t)1024 * 1536 * 2);
  size_t zbytes = off;
  // --- rest ---
  float* XF = (float*)alloc((size_t)2048 * 2048 * 4);
  float* XB = (float*)alloc((size_t)2048 * 2048 * 4);
  float* XD = (float*)alloc((size_t)1024 * 2048 * 4);
  float* EF = (float*)alloc((size_t)2048 * 1024 * 4);
  unsigned short* ENCO = (unsigned short*)alloc((size_t)2048 * 1024 * 2);
  unsigned short* EMBB = (unsigned short*)alloc((size_t)2048 * 256 * 2);
  unsigned short* DEMB = (unsigned short*)alloc((size_t)1024 * 256 * 2);
  float* HFIN = (float*)alloc((size_t)4 * 16384 * 4);   // hf,hb,cf,cb
  float* DFb  = (float*)alloc((size_t)32 * 1024 * 4);

  hipMemsetAsync(d_ws, 0, zbytes, stream);

  gather_enc_kernel<<<2048, 64, 0, stream>>>(enc_texts, enc_emb, EMBB);
  gather_dec_kernel<<<1024, 64, 0, stream>>>(dec_texts, dec_emb, DEMB);

  dim3 blk(256);
  // XF = emb @ Wih_f^T + b_f ; XB = emb @ Wih_b^T + b_b
  gemm_bt_kernel<<<dim3(16, 16), blk, 0, stream>>>(EMBB, 256, Wih_f, 256, 0, b_f, XF, 2048, 2048, 256);
  gemm_bt_kernel<<<dim3(16, 16), blk, 0, stream>>>(EMBB, 256, Wih_b, 256, 0, b_b, XB, 2048, 2048, 256);
  // XD = dec_in @ Wih_d[:, :256]^T + b_d
  gemm_bt_kernel<<<dim3(8, 16), blk, 0, stream>>>(DEMB, 256, Wih_d, 1280, 0, b_d, XD, 2048, 1024, 256);

  for (int s = 0; s < 64; ++s)
    enc_step_kernel<<<256, 256, 0, stream>>>(XF, XB, Whh_f, Whh_b, enc_mask, HENC, ENCO, HFIN, s);

  // enc_feat = enc_output @ W_ef^T + b_ef
  gemm_bt_kernel<<<dim3(16, 8), blk, 0, stream>>>(ENCO, 1024, W_ef, 1024, 0, b_ef, EF, 1024, 2048, 1024);
  dec_init_kernel<<<128, 256, 0, stream>>>(HFIN, W_h, b_h, W_c, b_c, HDEC);

  for (int t = 0; t < 31; ++t) {
    dec_gates_kernel<<<128, 256, 0, stream>>>(XD, Wih_d, Whh_d, HDEC, CTX, ACAT, t);
    dec_df_kernel<<<64, 256, 0, stream>>>(HDEC, W_df, b_df, DFb, t);
    dec_attn_kernel<<<32, 256, 0, stream>>>(DFb, EF, ENCO, enc_mask, CTX, ACAT, t);
  }

  // logits = [h, ctx] @ W_out^T + b_out  (97.5 GFLOP)
  gemm_bt_kernel<<<dim3(8, 250), blk, 0, stream>>>(ACAT, 1536, W_out, 1536, 0, b_out, out, 32000, 992, 1536);
}